// Round 8
// baseline (80.314 us; speedup 1.0000x reference)
//
#include <hip/hip_runtime.h>

#define MARGIN 0.15f
#define EPS 1e-8f
#define DD 256           // feature dim (fixed: samples are [512, 256] f32)
#define NN 512           // rows
#define SB 4             // anchor sub-batch per block (span <= 4 for bench data)
#define NBLK 192         // triplet chunks = blocks

// ---------------------------------------------------------------------------
// Kernel 1: self-contained triplet-chunk kernel. No cross-block deps at all.
// Block b owns triplets [b*T/NBLK, (b+1)*T/NBLK). ai is sorted, so the chunk
// touches a contiguous anchor span [alo, ahi] (typ. <= 4; SB-loop if wider).
// The block streams all of X once (L2-resident), computing for its <=SB
// anchors the raw dot rows dp[a][j] (j=0..511) and all row norms, stores them
// in LDS, then computes its chunk's hinges from LDS and writes ONE partial.
//   cos(a,j) = dp/max(|a||j|, EPS)  — identical formula to rounds 1-7
//   (absmax 0.0), loss term = dp_an/den_an - dp_ap/den_ap + margin, relu'd.
// Layout: 16-lane groups; lane (s = lane&15) owns k-slices {c*64 + s*4 ..+3},
// group (lane>>4) owns row j; anchors live in VGPRs (SB x 4 float4); 4-level
// shuffle reduce per row. All orders fixed -> deterministic.
// ---------------------------------------------------------------------------
__global__ __launch_bounds__(256) void chunk_fused(
    const float* __restrict__ X,
    const int* __restrict__ ai, const int* __restrict__ pi,
    const int* __restrict__ ni,
    float* __restrict__ partial, int T) {

    __shared__ float g_l[SB][NN];   // raw dot(anchor_i, row_j)
    __shared__ float rn_l[NN];      // ||row_j||
    __shared__ float red[4];

    int t   = threadIdx.x;
    int bid = blockIdx.x;
    int t0 = (int)((long long)bid * T / NBLK);
    int t1 = (int)((long long)(bid + 1) * T / NBLK);
    if (t0 >= t1) { if (t == 0) partial[bid] = 0.f; return; }

    int alo = ai[t0];
    int ahi = ai[t1 - 1];

    int w = t >> 6, lane = t & 63, s = lane & 15, grp = lane >> 4;
    const float4* X4 = (const float4*)X;

    float sum = 0.f;
    bool first = true;
    for (int ab = alo; ab <= ahi; ab += SB) {
        // anchor slices in registers: xa[i][c] = X[ab+i][c*64 + s*4 ..+3]
        float4 xa[SB][4];
#pragma unroll
        for (int i = 0; i < SB; ++i) {
            int ar = ab + i; if (ar > NN - 1) ar = NN - 1;   // clamp (unused rows)
#pragma unroll
            for (int c = 0; c < 4; ++c)
                xa[i][c] = X4[ar * 64 + c * 16 + s];
        }
        // sweep all 512 rows; block covers 16 rows/iter (4 waves x 4 groups)
        for (int it = 0; it < 32; ++it) {
            int j = it * 16 + w * 4 + grp;
            float4 xj[4];
#pragma unroll
            for (int c = 0; c < 4; ++c) xj[c] = X4[j * 64 + c * 16 + s];
            float dp[SB];
#pragma unroll
            for (int i = 0; i < SB; ++i) dp[i] = 0.f;
            float ssv = 0.f;
#pragma unroll
            for (int c = 0; c < 4; ++c) {
                float4 v = xj[c];
                ssv += v.x * v.x + v.y * v.y + v.z * v.z + v.w * v.w;
#pragma unroll
                for (int i = 0; i < SB; ++i) {
                    float4 a = xa[i][c];
                    dp[i] += a.x * v.x + a.y * v.y + a.z * v.z + a.w * v.w;
                }
            }
            // reduce across the 16 lanes of this group (fixed order)
#pragma unroll
            for (int o = 1; o < 16; o <<= 1) {
#pragma unroll
                for (int i = 0; i < SB; ++i) dp[i] += __shfl_xor(dp[i], o);
                ssv += __shfl_xor(ssv, o);
            }
            if (s == 0) {
#pragma unroll
                for (int i = 0; i < SB; ++i) g_l[i][j] = dp[i];
                if (first) rn_l[j] = ssv;
            }
        }
        __syncthreads();
        if (first) {
            for (int jj = t; jj < NN; jj += 256) rn_l[jj] = sqrtf(rn_l[jj]);
            __syncthreads();
        }
        // hinge pass for triplets whose anchor falls in [ab, ab+SB)
        int hi = ab + SB;
        for (int k = t0 + t; k < t1; k += 256) {
            int a = ai[k];
            if (a < ab || a >= hi) continue;
            int p = pi[k], n = ni[k];
            float rna = rn_l[a];
            float vdn = g_l[a - ab][n] / fmaxf(rna * rn_l[n], EPS);
            float vdp = g_l[a - ab][p] / fmaxf(rna * rn_l[p], EPS);
            float v = vdn - vdp + MARGIN;
            sum += v > 0.f ? v : 0.f;
        }
        __syncthreads();            // g_l reused next sub-batch
        first = false;
    }
    // deterministic block reduce -> one partial
#pragma unroll
    for (int o = 32; o; o >>= 1) sum += __shfl_xor(sum, o);
    if (lane == 0) red[w] = sum;
    __syncthreads();
    if (t == 0) partial[bid] = red[0] + red[1] + red[2] + red[3];
}

// ---------------------------------------------------------------------------
// Kernel 2: fixed-order final reduce over block partials, scale by 1/T.
// ---------------------------------------------------------------------------
__global__ __launch_bounds__(256) void reduce_partials(const float* __restrict__ partial,
                                                       int nb, float invT,
                                                       float* __restrict__ out) {
    float s = 0.f;
    for (int i = threadIdx.x; i < nb; i += 256) s += partial[i];
#pragma unroll
    for (int off = 32; off; off >>= 1) s += __shfl_xor(s, off);
    __shared__ float red[4];
    int wid = threadIdx.x >> 6;
    if ((threadIdx.x & 63) == 0) red[wid] = s;
    __syncthreads();
    if (threadIdx.x == 0) out[0] = (red[0] + red[1] + red[2] + red[3]) * invT;
}

// ---------------------------------------------------------------------------
// Fallback kernels (odd shapes / tiny ws): norms + direct dots + reduce.
// ---------------------------------------------------------------------------
__global__ __launch_bounds__(256) void norm_rows(const float* __restrict__ X,
                                                 float* __restrict__ rnorm, int N) {
    int row = blockIdx.x * 4 + (threadIdx.x >> 6);
    if (row >= N) return;
    int lane = threadIdx.x & 63;
    float4 v = ((const float4*)(X + (size_t)row * DD))[lane];
    float ss = v.x * v.x + v.y * v.y + v.z * v.z + v.w * v.w;
#pragma unroll
    for (int off = 32; off; off >>= 1) ss += __shfl_xor(ss, off);
    if (lane == 0) rnorm[row] = sqrtf(ss);
}

__global__ __launch_bounds__(256) void triplet_direct(const float* __restrict__ X,
                                                      const float* __restrict__ rnorm,
                                                      const int* __restrict__ ai,
                                                      const int* __restrict__ pi,
                                                      const int* __restrict__ ni,
                                                      float* __restrict__ partial,
                                                      int T, int N) {
    float sum = 0.f;
    for (int t = blockIdx.x * blockDim.x + threadIdx.x; t < T;
         t += gridDim.x * blockDim.x) {
        int a = ai[t], p = pi[t], n = ni[t];
        const float4* xa = (const float4*)(X + (size_t)a * DD);
        const float4* xp = (const float4*)(X + (size_t)p * DD);
        const float4* xn = (const float4*)(X + (size_t)n * DD);
        float dp = 0.f, dn = 0.f;
#pragma unroll 4
        for (int k = 0; k < DD / 4; ++k) {
            float4 av = xa[k], pv = xp[k], nv = xn[k];
            dp += av.x * pv.x + av.y * pv.y + av.z * pv.z + av.w * pv.w;
            dn += av.x * nv.x + av.y * nv.y + av.z * nv.z + av.w * nv.w;
        }
        float na = rnorm[a];
        float v = dn / fmaxf(na * rnorm[n], EPS) - dp / fmaxf(na * rnorm[p], EPS) + MARGIN;
        sum += v > 0.f ? v : 0.f;
    }
#pragma unroll
    for (int off = 32; off; off >>= 1) sum += __shfl_xor(sum, off);
    __shared__ float red[4];
    int wid = threadIdx.x >> 6;
    if ((threadIdx.x & 63) == 0) red[wid] = sum;
    __syncthreads();
    if (threadIdx.x == 0) partial[blockIdx.x] = red[0] + red[1] + red[2] + red[3];
}

extern "C" void kernel_launch(void* const* d_in, const int* in_sizes, int n_in,
                              void* d_out, int out_size, void* d_ws, size_t ws_size,
                              hipStream_t stream) {
    const float* X  = (const float*)d_in[0];   // samples [N, D] f32
    const int*   ai = (const int*)d_in[2];     // anchor_idx [T] (sorted runs)
    const int*   pi = (const int*)d_in[3];     // pos_idx [T]
    const int*   ni = (const int*)d_in[4];     // neg_idx [T]
    float* out = (float*)d_out;

    int N = in_sizes[1];                       // 512
    int T = in_sizes[2];

    if (N == NN && in_sizes[0] == NN * DD && T > 0 &&
        ws_size >= (size_t)NBLK * sizeof(float)) {
        // Path A: 2 dispatches, zero cross-block sync
        float* partial = (float*)d_ws;
        chunk_fused<<<NBLK, 256, 0, stream>>>(X, ai, pi, ni, partial, T);
        reduce_partials<<<1, 256, 0, stream>>>(partial, NBLK, 1.0f / (float)T, out);
    } else {
        // Path B: norms + direct per-triplet dots + reduce (3 dispatches)
        float* rnorm   = (float*)d_ws;
        float* partial = rnorm + N;
        int NB = (T + 255) / 256;
        if (NB > 2048) NB = 2048;
        if (NB < 1) NB = 1;
        norm_rows<<<(N + 3) / 4, 256, 0, stream>>>(X, rnorm, N);
        triplet_direct<<<NB, 256, 0, stream>>>(X, rnorm, ai, pi, ni, partial, T, N);
        reduce_partials<<<1, 256, 0, stream>>>(partial, NB, 1.0f / (float)T, out);
    }
}

// Round 9
// 15.639 us; speedup vs baseline: 5.1355x; 5.1355x over previous
//
#include <hip/hip_runtime.h>

#define MARGIN 0.15f
#define EPS 1e-8f
#define D 256            // feature dim (fixed: samples are [512, 256] f32)
#define GT 32            // gram tile
#define LDP (D + 4)      // padded LDS row stride (floats), 16B-aligned rows
#define NWB 256          // worker blocks in kernel 2 == gram grid blocks
#define SLOT_U32 32      // u32 stride per slot line (128 B)
#define SENT 0xFFFFFFFFu // NaN bit pattern; worker partials are finite >= 0

// ---------------------------------------------------------------------------
// Kernel 1: fused row-norm + Gram tile (body proven r2-r8, absmax 0.0).
// G[a,b] = dot(X_a,X_b)/max(|a||b|,EPS) — exactly the reference cosine form.
// Each of the 256 blocks also plain-stores the sentinel into ITS OWN slot
// line for kernel 2 (distributed init; cross-dispatch store->atomic
// visibility proven in r5/r6).
// ---------------------------------------------------------------------------
__global__ __launch_bounds__(256) void norm_gram(const float* __restrict__ X,
                                                 float* __restrict__ G,
                                                 unsigned int* __restrict__ slots,
                                                 int N) {
    __shared__ float As[GT][LDP];
    __shared__ float Bs[GT][LDP];
    __shared__ float na[GT], nb[GT];
    int t = threadIdx.x;
    if (t == 0) {
        int id = blockIdx.y * gridDim.x + blockIdx.x;   // 0..255
        slots[id * SLOT_U32] = SENT;
    }

    const float4* A4 = (const float4*)(X + (size_t)blockIdx.y * GT * D);
    const float4* B4 = (const float4*)(X + (size_t)blockIdx.x * GT * D);
#pragma unroll
    for (int i = 0; i < 8; ++i) {
        int f = t + i * 256;          // 0..2047 float4s per 32x256 tile
        int r = f >> 6, c = f & 63;
        *(float4*)&As[r][c * 4] = A4[f];
        *(float4*)&Bs[r][c * 4] = B4[f];
    }
    __syncthreads();

    // Row norms from LDS: 8 adjacent lanes per row.
    {
        int row = t >> 3, sub = t & 7;
        float ssA = 0.f, ssB = 0.f;
#pragma unroll
        for (int j = 0; j < 8; ++j) {
            float4 a = *(const float4*)&As[row][(sub * 8 + j) * 4];
            ssA += a.x * a.x + a.y * a.y + a.z * a.z + a.w * a.w;
            float4 b = *(const float4*)&Bs[row][(sub * 8 + j) * 4];
            ssB += b.x * b.x + b.y * b.y + b.z * b.z + b.w * b.w;
        }
#pragma unroll
        for (int off = 1; off < 8; off <<= 1) {
            ssA += __shfl_xor(ssA, off);
            ssB += __shfl_xor(ssB, off);
        }
        if (sub == 0) { na[row] = sqrtf(ssA); nb[row] = sqrtf(ssB); }
    }
    __syncthreads();

    int tx = t & 15, ty = t >> 4;
    int r0 = ty * 2, c0 = tx * 2;
    float acc00 = 0.f, acc01 = 0.f, acc10 = 0.f, acc11 = 0.f;
#pragma unroll 4
    for (int k = 0; k < D; k += 4) {
        float4 a0 = *(const float4*)&As[r0][k];
        float4 a1 = *(const float4*)&As[r0 + 1][k];
        float4 b0 = *(const float4*)&Bs[c0][k];
        float4 b1 = *(const float4*)&Bs[c0 + 1][k];
        acc00 += a0.x * b0.x + a0.y * b0.y + a0.z * b0.z + a0.w * b0.w;
        acc01 += a0.x * b1.x + a0.y * b1.y + a0.z * b1.z + a0.w * b1.w;
        acc10 += a1.x * b0.x + a1.y * b0.y + a1.z * b0.z + a1.w * b0.w;
        acc11 += a1.x * b1.x + a1.y * b1.y + a1.z * b1.z + a1.w * b1.w;
    }
    float nA0 = na[r0], nA1 = na[r0 + 1], nB0 = nb[c0], nB1 = nb[c0 + 1];
    size_t orow = (size_t)(blockIdx.y * GT + r0) * N + blockIdx.x * GT + c0;
    float2 o0 = {acc00 / fmaxf(nA0 * nB0, EPS), acc01 / fmaxf(nA0 * nB1, EPS)};
    float2 o1 = {acc10 / fmaxf(nA1 * nB0, EPS), acc11 / fmaxf(nA1 * nB1, EPS)};
    *(float2*)&G[orow]     = o0;
    *(float2*)&G[orow + N] = o1;
}

// ---------------------------------------------------------------------------
// Kernel 2: triplet hinge gather (r4-proven int2 form, 256 blocks = 4 waves/CU)
// + sentinel-slot finisher.  Each block publishes its fixed-order partial with
// ONE atomicExch to its own 128B line (256 parallel lines, no serialization).
// Block 0 then spin-reads slot i on lane i (atomic loads, distinct lines,
// s_sleep backoff) until non-sentinel, and does a fixed-order tree -> out.
// All blocks co-resident (no LDS pressure, 4 waves) -> no deadlock.
// d_pos - d_neg + m = G[a,n] - G[a,p] + m.
// ---------------------------------------------------------------------------
__global__ __launch_bounds__(256) void triplet_finish(
    const float* __restrict__ G, const int* __restrict__ ai,
    const int* __restrict__ pi, const int* __restrict__ ni,
    unsigned int* __restrict__ slots, int T, int N, float invT,
    float* __restrict__ out) {
    const int2* ai2 = (const int2*)ai;
    const int2* pi2 = (const int2*)pi;
    const int2* ni2 = (const int2*)ni;
    int half = T >> 1;
    float sum = 0.f;
    int t = threadIdx.x;
    int tid = blockIdx.x * 256 + t;
    int stride = NWB * 256;
    for (int k = tid; k < half; k += stride) {
        int2 a = ai2[k], p = pi2[k], n = ni2[k];
        float v0 = G[a.x * N + n.x] - G[a.x * N + p.x] + MARGIN;
        float v1 = G[a.y * N + n.y] - G[a.y * N + p.y] + MARGIN;
        sum += (v0 > 0.f ? v0 : 0.f) + (v1 > 0.f ? v1 : 0.f);
    }
    if (tid == 0 && (T & 1)) {
        int k = T - 1;
        float v = G[ai[k] * N + ni[k]] - G[ai[k] * N + pi[k]] + MARGIN;
        sum += v > 0.f ? v : 0.f;
    }
#pragma unroll
    for (int off = 32; off; off >>= 1) sum += __shfl_xor(sum, off);
    __shared__ float red[4];
    int wid = t >> 6;
    if ((t & 63) == 0) red[wid] = sum;
    __syncthreads();
    if (t == 0) {
        float bsum = red[0] + red[1] + red[2] + red[3];   // finite, >= 0
        atomicExch(&slots[blockIdx.x * SLOT_U32], __float_as_uint(bsum));
    }
    // ---- finisher: block 0, lane i waits on slot i (one slot per thread) ----
    if (blockIdx.x == 0) {
        unsigned int u = atomicAdd(&slots[t * SLOT_U32], 0u);
        while (u == SENT) {
            __builtin_amdgcn_s_sleep(2);
            u = atomicAdd(&slots[t * SLOT_U32], 0u);
        }
        float s = __uint_as_float(u);
#pragma unroll
        for (int off = 32; off; off >>= 1) s += __shfl_xor(s, off);
        if ((t & 63) == 0) red[wid] = s;
        __syncthreads();
        if (t == 0) out[0] = (red[0] + red[1] + red[2] + red[3]) * invT;
    }
}

// ---------------------------------------------------------------------------
// Fallback kernels (odd shapes / tiny ws): norms + direct dots + reduce.
// ---------------------------------------------------------------------------
__global__ __launch_bounds__(256) void norm_rows(const float* __restrict__ X,
                                                 float* __restrict__ rnorm, int N) {
    int row = blockIdx.x * 4 + (threadIdx.x >> 6);
    if (row >= N) return;
    int lane = threadIdx.x & 63;
    float4 v = ((const float4*)(X + (size_t)row * D))[lane];
    float ss = v.x * v.x + v.y * v.y + v.z * v.z + v.w * v.w;
#pragma unroll
    for (int off = 32; off; off >>= 1) ss += __shfl_xor(ss, off);
    if (lane == 0) rnorm[row] = sqrtf(ss);
}

__global__ __launch_bounds__(256) void triplet_direct(const float* __restrict__ X,
                                                      const float* __restrict__ rnorm,
                                                      const int* __restrict__ ai,
                                                      const int* __restrict__ pi,
                                                      const int* __restrict__ ni,
                                                      float* __restrict__ partial,
                                                      int T, int N) {
    float sum = 0.f;
    for (int t = blockIdx.x * blockDim.x + threadIdx.x; t < T;
         t += gridDim.x * blockDim.x) {
        int a = ai[t], p = pi[t], n = ni[t];
        const float4* xa = (const float4*)(X + (size_t)a * D);
        const float4* xp = (const float4*)(X + (size_t)p * D);
        const float4* xn = (const float4*)(X + (size_t)n * D);
        float dp = 0.f, dn = 0.f;
#pragma unroll 4
        for (int k = 0; k < D / 4; ++k) {
            float4 av = xa[k], pv = xp[k], nv = xn[k];
            dp += av.x * pv.x + av.y * pv.y + av.z * pv.z + av.w * pv.w;
            dn += av.x * nv.x + av.y * nv.y + av.z * nv.z + av.w * nv.w;
        }
        float na = rnorm[a];
        float v = dn / fmaxf(na * rnorm[n], EPS) - dp / fmaxf(na * rnorm[p], EPS) + MARGIN;
        sum += v > 0.f ? v : 0.f;
    }
#pragma unroll
    for (int off = 32; off; off >>= 1) sum += __shfl_xor(sum, off);
    __shared__ float red[4];
    int wid = threadIdx.x >> 6;
    if ((threadIdx.x & 63) == 0) red[wid] = sum;
    __syncthreads();
    if (threadIdx.x == 0) partial[blockIdx.x] = red[0] + red[1] + red[2] + red[3];
}

__global__ __launch_bounds__(256) void reduce_partials(const float* __restrict__ partial,
                                                       int nb, float invT,
                                                       float* __restrict__ out) {
    float s = 0.f;
    for (int i = threadIdx.x; i < nb; i += 256) s += partial[i];
#pragma unroll
    for (int off = 32; off; off >>= 1) s += __shfl_xor(s, off);
    __shared__ float red[4];
    int wid = threadIdx.x >> 6;
    if ((threadIdx.x & 63) == 0) red[wid] = s;
    __syncthreads();
    if (threadIdx.x == 0) out[0] = (red[0] + red[1] + red[2] + red[3]) * invT;
}

extern "C" void kernel_launch(void* const* d_in, const int* in_sizes, int n_in,
                              void* d_out, int out_size, void* d_ws, size_t ws_size,
                              hipStream_t stream) {
    const float* X  = (const float*)d_in[0];   // samples [N, D] f32
    const int*   ai = (const int*)d_in[2];     // anchor_idx [T]
    const int*   pi = (const int*)d_in[3];     // pos_idx [T]
    const int*   ni = (const int*)d_in[4];     // neg_idx [T]
    float* out = (float*)d_out;

    int N = in_sizes[1];                       // 512
    int T = in_sizes[2];

    size_t gB    = (size_t)N * N * sizeof(float);
    size_t slotB = (size_t)NWB * SLOT_U32 * sizeof(unsigned int);

    if (ws_size >= gB + slotB && (N % GT) == 0 && (N / GT) * (N / GT) == NWB &&
        T > 0) {
        // Path A: norm+gram (+sentinel init) -> gather + sentinel finisher
        float*        G     = (float*)d_ws;
        unsigned int* slots = (unsigned int*)((char*)d_ws + gB);
        dim3 gg(N / GT, N / GT);               // 16x16 = 256 = NWB
        norm_gram<<<gg, 256, 0, stream>>>(X, G, slots, N);
        triplet_finish<<<NWB, 256, 0, stream>>>(G, ai, pi, ni, slots,
                                                T, N, 1.0f / (float)T, out);
    } else {
        // Path B: norms + direct per-triplet dots + reduce (3 dispatches)
        float* rnorm   = (float*)d_ws;
        float* partial = rnorm + N;
        int NB = (T + 255) / 256;
        if (NB > 2048) NB = 2048;
        if (NB < 1) NB = 1;
        norm_rows<<<(N + 3) / 4, 256, 0, stream>>>(X, rnorm, N);
        triplet_direct<<<NB, 256, 0, stream>>>(X, rnorm, ai, pi, ni, partial, T, N);
        reduce_partials<<<1, 256, 0, stream>>>(partial, NB, 1.0f / (float)T, out);
    }
}